// Round 4
// baseline (123.492 us; speedup 1.0000x reference)
//
#include <hip/hip_runtime.h>
#include <math.h>

#define INVT (1.0f / 0.07f)
#define CSHIFT (1.0f / 0.07f)

using bf16x8 = __attribute__((ext_vector_type(8))) short;
using f32x4  = __attribute__((ext_vector_type(4))) float;

__device__ __forceinline__ int lower_bound_i(const int* a, int n, int v) {
    int lo = 0, hi = n;
    while (lo < hi) { int mid = (lo + hi) >> 1; if (a[mid] < v) lo = mid + 1; else hi = mid; }
    return lo;
}

__device__ __forceinline__ unsigned short f2bf(float x) {
    unsigned int u = __float_as_uint(x);
    unsigned int r = (u + 0x7fffu + ((u >> 16) & 1u)) >> 16;   // RNE
    return (unsigned short)r;
}

// ---------------- kernel 1: normalize + bf16 tiled convert + meta (block 0) ----------------
// Tiled layout: row_tile rt = i>>4 (16 rows), k_tile kt = k>>5 (32 k). Tile = 512 bf16 (1KB).
// Slot s in tile holds row r = s&15, k = kt*32 + (s>>4)*8 .. +7  => k_main lane l reads slot l.
__global__ void k_prep(const float* __restrict__ fb, const float* __restrict__ fd,
                       int Nb, int Nd, int D,
                       unsigned short* __restrict__ fbt, unsigned short* __restrict__ fdt,
                       float* __restrict__ rowsumA,
                       const int* __restrict__ td, const int* __restrict__ bd,
                       const int* __restrict__ im, const int* __restrict__ ut, int G,
                       int* __restrict__ mouth_word, int* __restrict__ group_batch,
                       int* __restrict__ group_is_mouth,
                       int* __restrict__ col_g, int* __restrict__ col_gb,
                       int* __restrict__ col_gm, int* __restrict__ col_gc,
                       float* __restrict__ numv, float* __restrict__ t1v,
                       float* __restrict__ t3v, unsigned int* __restrict__ done) {
    int gw = (blockIdx.x * blockDim.x + threadIdx.x) >> 6;
    int lane = threadIdx.x & 63;
    int ktiles = D >> 5;
    if (gw < Nb + Nd) {
        const float* row; unsigned short* ob; int rt, r;
        if (gw < Nb) {
            row = fb + (size_t)gw * D; ob = fbt; rt = gw >> 4; r = gw & 15;
            if (lane == 0) rowsumA[gw] = 0.f;
        } else {
            int j = gw - Nb;
            row = fd + (size_t)j * D; ob = fdt; rt = j >> 4; r = j & 15;
        }
        float s = 0.f;
        for (int d = lane * 4; d < D; d += 256) {
            float4 v = *(const float4*)(row + d);
            s += v.x * v.x + v.y * v.y + v.z * v.z + v.w * v.w;
        }
        #pragma unroll
        for (int m = 32; m >= 1; m >>= 1) s += __shfl_xor(s, m, 64);
        float inv = rsqrtf(s);
        for (int d = lane * 4; d < D; d += 256) {
            float4 v = *(const float4*)(row + d);
            ushort4 o;
            o.x = f2bf(v.x * inv); o.y = f2bf(v.y * inv);
            o.z = f2bf(v.z * inv); o.w = f2bf(v.w * inv);
            int kt = d >> 5, kk = d & 31;
            int slot = (kk >> 3) * 16 + r, elem = kk & 7;
            *(ushort4*)(ob + (((size_t)(rt * ktiles + kt)) << 9) + slot * 8 + elem) = o;
        }
    }
    if (blockIdx.x == 0) {
        int t = threadIdx.x;
        if (t == 0) *done = 0u;
        for (int i = t; i < Nb; i += blockDim.x) mouth_word[i] = -1;
        for (int g = t; g < G; g += blockDim.x) {
            group_batch[g] = -1; group_is_mouth[g] = -1;
            numv[g] = 0.f; t1v[g] = 0.f; t3v[g] = 0.f;
        }
        __syncthreads();
        for (int j = t; j < Nd; j += blockDim.x) {
            int g = lower_bound_i(ut, G, td[j]);
            col_g[j] = g;
            atomicMax(&group_batch[g], bd[j]);
            atomicMax(&group_is_mouth[g], im[j]);
            if (im[j] == 1) atomicMax(&mouth_word[bd[j]], td[j]);
        }
        __syncthreads();
        for (int j = t; j < Nd; j += blockDim.x) {
            int g = col_g[j];
            col_gb[j] = group_batch[g];
            col_gm[j] = group_is_mouth[g];
            col_gc[j] = ut[g];
        }
    }
}

// ---------------- kernel 2: MFMA GEMM + fused epilogue + last-block finish ----------------
__global__ __launch_bounds__(256, 4)
void k_main(const unsigned short* __restrict__ fbt, const unsigned short* __restrict__ fdt,
            const int* __restrict__ tb, const int* __restrict__ bb_arr,
            const int* __restrict__ mouth_word,
            const int* __restrict__ col_g, const int* __restrict__ col_gb,
            const int* __restrict__ col_gm, const int* __restrict__ col_gc,
            int Nb, int Nd, int D, int G, int nblk,
            float* __restrict__ rowsumA, float* __restrict__ numv,
            float* __restrict__ t1v, float* __restrict__ t3v,
            unsigned int* __restrict__ done,
            const int* __restrict__ ut, const int* __restrict__ group_batch,
            const int* __restrict__ group_is_mouth, float* __restrict__ out) {
    __shared__ float cnum[64], ct1[64], ct3[64], rsum[64];
    __shared__ int lastflag;

    int t = threadIdx.x, lane = t & 63, wid = t >> 6;
    int wr = wid >> 1, wc = wid & 1;
    int bm = blockIdx.x * 64, bn = blockIdx.y * 64;
    int l15 = lane & 15, lhi = lane >> 4;

    if (t < 64) { cnum[t] = 0.f; ct1[t] = 0.f; ct3[t] = 0.f; rsum[t] = 0.f; }

    int ktiles = D >> 5;
    const unsigned short* a0p = fbt + (((size_t)(((bm >> 4) + wr * 2) * ktiles)) << 9) + lane * 8;
    const unsigned short* a1p = a0p + ((size_t)ktiles << 9);
    const unsigned short* b0p = fdt + (((size_t)(((bn >> 4) + wc * 2) * ktiles)) << 9) + lane * 8;
    const unsigned short* b1p = b0p + ((size_t)ktiles << 9);

    f32x4 acc[2][2] = {};
    #pragma unroll 8
    for (int kt = 0; kt < ktiles; ++kt) {
        size_t o = (size_t)kt << 9;
        bf16x8 a0 = *(const bf16x8*)(a0p + o);
        bf16x8 a1 = *(const bf16x8*)(a1p + o);
        bf16x8 b0 = *(const bf16x8*)(b0p + o);
        bf16x8 b1 = *(const bf16x8*)(b1p + o);
        acc[0][0] = __builtin_amdgcn_mfma_f32_16x16x32_bf16(a0, b0, acc[0][0], 0, 0, 0);
        acc[0][1] = __builtin_amdgcn_mfma_f32_16x16x32_bf16(a0, b1, acc[0][1], 0, 0, 0);
        acc[1][0] = __builtin_amdgcn_mfma_f32_16x16x32_bf16(a1, b0, acc[1][0], 0, 0, 0);
        acc[1][1] = __builtin_amdgcn_mfma_f32_16x16x32_bf16(a1, b1, acc[1][1], 0, 0, 0);
    }

    // ---- epilogue ----
    int cgb[2], cgm[2], cgc[2];
    #pragma unroll
    for (int nj = 0; nj < 2; ++nj) {
        int col = bn + wc * 32 + nj * 16 + l15;
        cgb[nj] = col_gb[col]; cgm[nj] = col_gm[col]; cgc[nj] = col_gc[col];
    }

    float pnum[2] = {0.f, 0.f}, pt1[2] = {0.f, 0.f}, pt3[2] = {0.f, 0.f};
    float prow[2][4];

    #pragma unroll
    for (int mi = 0; mi < 2; ++mi) {
        #pragma unroll
        for (int r = 0; r < 4; ++r) {
            int i = bm + wr * 32 + mi * 16 + lhi * 4 + r;
            int tbi = tb[i], bbi = bb_arr[i];
            int mw = mouth_word[bbi];
            bool fg = (tbi != -1);
            float pr = 0.f;
            #pragma unroll
            for (int nj = 0; nj < 2; ++nj) {
                float e = __expf(acc[mi][nj][r] * INVT - CSHIFT);
                bool match = fg ? (cgc[nj] == mw) : ((cgb[nj] == bbi) && (cgm[nj] == 0));
                float a = (match && (bbi != cgb[nj])) ? 0.f : e;
                pnum[nj] += match ? e : 0.f;
                pt1[nj] += a;
                pt3[nj] += match ? a : 0.f;
                pr += a;
            }
            prow[mi][r] = pr;
        }
    }

    __syncthreads();   // LDS zero-init visible

    #pragma unroll
    for (int nj = 0; nj < 2; ++nj) {
        float n = pnum[nj], x1 = pt1[nj], x3 = pt3[nj];
        n  += __shfl_xor(n, 16, 64);  n  += __shfl_xor(n, 32, 64);
        x1 += __shfl_xor(x1, 16, 64); x1 += __shfl_xor(x1, 32, 64);
        x3 += __shfl_xor(x3, 16, 64); x3 += __shfl_xor(x3, 32, 64);
        if (lhi == 0) {
            int c = wc * 32 + nj * 16 + l15;
            atomicAdd(&cnum[c], n); atomicAdd(&ct1[c], x1); atomicAdd(&ct3[c], x3);
        }
    }
    #pragma unroll
    for (int mi = 0; mi < 2; ++mi) {
        #pragma unroll
        for (int r = 0; r < 4; ++r) {
            float v = prow[mi][r];
            v += __shfl_xor(v, 1, 64); v += __shfl_xor(v, 2, 64);
            v += __shfl_xor(v, 4, 64); v += __shfl_xor(v, 8, 64);
            if (l15 == 0) atomicAdd(&rsum[wr * 32 + mi * 16 + lhi * 4 + r], v);
        }
    }
    __syncthreads();

    if (t < 16) {
        int base = bn + t * 4;
        int g0 = col_g[base];
        float sn = cnum[4*t] + cnum[4*t+1] + cnum[4*t+2] + cnum[4*t+3];
        float s1 = ct1[4*t] + ct1[4*t+1] + ct1[4*t+2] + ct1[4*t+3];
        float s3 = ct3[4*t] + ct3[4*t+1] + ct3[4*t+2] + ct3[4*t+3];
        if (col_g[base+1] == g0 && col_g[base+2] == g0 && col_g[base+3] == g0) {
            atomicAdd(&numv[g0], sn); atomicAdd(&t1v[g0], s1); atomicAdd(&t3v[g0], s3);
        } else {
            #pragma unroll
            for (int c = 0; c < 4; ++c) {
                int g = col_g[base + c];
                atomicAdd(&numv[g], cnum[4*t+c]);
                atomicAdd(&t1v[g], ct1[4*t+c]);
                atomicAdd(&t3v[g], ct3[4*t+c]);
            }
        }
    } else if (t >= 64 && t < 128) {
        int r = t - 64;
        atomicAdd(&rowsumA[bm + r], rsum[r]);
    }

    // ---- last-block finish: t2 + loss ----
    __threadfence();
    __syncthreads();
    if (t == 0) {
        unsigned int old = atomicAdd(done, 1u);
        lastflag = (old == (unsigned int)(nblk - 1)) ? 1 : 0;
    }
    __syncthreads();
    if (!lastflag) return;
    __threadfence();

    __shared__ float t2g[1024], bgs[1024], red[256];
    for (int i = t; i < 1024; i += 256) { t2g[i] = 0.f; bgs[i] = 0.f; }
    __syncthreads();
    for (int i = t; i < Nb; i += 256) {
        float r = __hip_atomic_load(&rowsumA[i], __ATOMIC_RELAXED, __HIP_MEMORY_SCOPE_AGENT);
        int tbi = tb[i], bbi = bb_arr[i] & 1023;
        if (tbi != -1) {
            int g = lower_bound_i(ut, G, mouth_word[bbi]);
            atomicAdd(&t2g[g & 1023], r);
        } else {
            atomicAdd(&bgs[bbi], r);
        }
    }
    __syncthreads();
    float acc2 = 0.f;
    for (int g = t; g < G; g += 256) {
        float t2 = t2g[g & 1023];
        int gb = group_batch[g];
        if (group_is_mouth[g] == 0 && gb >= 0 && gb < 1024) t2 += bgs[gb];
        float den = __hip_atomic_load(&t1v[g], __ATOMIC_RELAXED, __HIP_MEMORY_SCOPE_AGENT)
                  + t2
                  - __hip_atomic_load(&t3v[g], __ATOMIC_RELAXED, __HIP_MEMORY_SCOPE_AGENT);
        float nm = __hip_atomic_load(&numv[g], __ATOMIC_RELAXED, __HIP_MEMORY_SCOPE_AGENT);
        acc2 += logf(den) - logf(nm);
    }
    red[t] = acc2;
    __syncthreads();
    for (int k = 128; k >= 1; k >>= 1) {
        if (t < k) red[t] += red[t + k];
        __syncthreads();
    }
    if (t == 0) out[0] = red[0] / (float)G;
}

extern "C" void kernel_launch(void* const* d_in, const int* in_sizes, int n_in,
                              void* d_out, int out_size, void* d_ws, size_t ws_size,
                              hipStream_t stream) {
    const float* fb = (const float*)d_in[0];
    const float* fd = (const float*)d_in[1];
    const int* tb = (const int*)d_in[2];
    const int* td = (const int*)d_in[3];
    const int* bb = (const int*)d_in[4];
    const int* bd = (const int*)d_in[5];
    const int* im = (const int*)d_in[6];
    const int* ut = (const int*)d_in[7];

    int Nb = in_sizes[2];
    int Nd = in_sizes[3];
    int G  = in_sizes[7];
    int D  = in_sizes[0] / Nb;
    float* out = (float*)d_out;

    char* p = (char*)d_ws;
    unsigned short* fbt = (unsigned short*)p; p += (size_t)Nb * D * sizeof(unsigned short);
    unsigned short* fdt = (unsigned short*)p; p += (size_t)Nd * D * sizeof(unsigned short);
    float* rowsumA = (float*)p; p += (size_t)Nb * sizeof(float);
    float* numv = (float*)p;    p += (size_t)G * sizeof(float);
    float* t1v = (float*)p;     p += (size_t)G * sizeof(float);
    float* t3v = (float*)p;     p += (size_t)G * sizeof(float);
    int* mouth_word = (int*)p;     p += (size_t)Nb * sizeof(int);
    int* group_batch = (int*)p;    p += (size_t)G * sizeof(int);
    int* group_is_mouth = (int*)p; p += (size_t)G * sizeof(int);
    int* col_g = (int*)p;  p += (size_t)Nd * sizeof(int);
    int* col_gb = (int*)p; p += (size_t)Nd * sizeof(int);
    int* col_gm = (int*)p; p += (size_t)Nd * sizeof(int);
    int* col_gc = (int*)p; p += (size_t)Nd * sizeof(int);
    unsigned int* done = (unsigned int*)p; p += sizeof(unsigned int);

    {
        int waves = Nb + Nd;
        int blocks = (waves + 3) / 4;
        k_prep<<<blocks, 256, 0, stream>>>(fb, fd, Nb, Nd, D, fbt, fdt, rowsumA,
                                           td, bd, im, ut, G,
                                           mouth_word, group_batch, group_is_mouth,
                                           col_g, col_gb, col_gm, col_gc,
                                           numv, t1v, t3v, done);
    }

    dim3 grid(Nb / 64, Nd / 64);
    int nblk = (Nb / 64) * (Nd / 64);
    k_main<<<grid, 256, 0, stream>>>(fbt, fdt, tb, bb, mouth_word,
                                     col_g, col_gb, col_gm, col_gc,
                                     Nb, Nd, D, G, nblk,
                                     rowsumA, numv, t1v, t3v, done,
                                     ut, group_batch, group_is_mouth, out);
}

// Round 5
// 64.125 us; speedup vs baseline: 1.9258x; 1.9258x over previous
//
#include <hip/hip_runtime.h>
#include <math.h>

#define INVT (1.0f / 0.07f)
#define CSHIFT (1.0f / 0.07f)

using bf16x8 = __attribute__((ext_vector_type(8))) short;
using f32x4  = __attribute__((ext_vector_type(4))) float;

__device__ __forceinline__ int lower_bound_i(const int* a, int n, int v) {
    int lo = 0, hi = n;
    while (lo < hi) { int mid = (lo + hi) >> 1; if (a[mid] < v) lo = mid + 1; else hi = mid; }
    return lo;
}

__device__ __forceinline__ unsigned short f2bf(float x) {
    unsigned int u = __float_as_uint(x);
    unsigned int r = (u + 0x7fffu + ((u >> 16) & 1u)) >> 16;   // RNE
    return (unsigned short)r;
}

// ---------------- kernel 1: normalize + bf16 tiled convert + meta (block 0) ----------------
// Tile = (16 rows x 32 k) = 512 bf16 (1KB). Slot s holds row s&15, k-chunk (s>>4)*8.
// => k_main lane l does one 16B load at tile_base + l*16: perfectly coalesced.
__global__ void k_prep(const float* __restrict__ fb, const float* __restrict__ fd,
                       int Nb, int Nd, int D,
                       unsigned short* __restrict__ fbt, unsigned short* __restrict__ fdt,
                       float* __restrict__ rowsumA,
                       const int* __restrict__ td, const int* __restrict__ bd,
                       const int* __restrict__ im, const int* __restrict__ ut, int G,
                       int* __restrict__ mouth_word, int* __restrict__ group_batch,
                       int* __restrict__ group_is_mouth,
                       int* __restrict__ col_g, int* __restrict__ col_gb,
                       int* __restrict__ col_gm, int* __restrict__ col_gc,
                       float* __restrict__ numv, float* __restrict__ t1v,
                       float* __restrict__ t3v) {
    int gw = (blockIdx.x * blockDim.x + threadIdx.x) >> 6;
    int lane = threadIdx.x & 63;
    int ktiles = D >> 5;
    if (gw < Nb + Nd) {
        const float* row; unsigned short* ob; int rt, r;
        if (gw < Nb) {
            row = fb + (size_t)gw * D; ob = fbt; rt = gw >> 4; r = gw & 15;
            if (lane == 0) rowsumA[gw] = 0.f;
        } else {
            int j = gw - Nb;
            row = fd + (size_t)j * D; ob = fdt; rt = j >> 4; r = j & 15;
        }
        float s = 0.f;
        for (int d = lane * 4; d < D; d += 256) {
            float4 v = *(const float4*)(row + d);
            s += v.x * v.x + v.y * v.y + v.z * v.z + v.w * v.w;
        }
        #pragma unroll
        for (int m = 32; m >= 1; m >>= 1) s += __shfl_xor(s, m, 64);
        float inv = rsqrtf(s);
        for (int d = lane * 4; d < D; d += 256) {
            float4 v = *(const float4*)(row + d);
            ushort4 o;
            o.x = f2bf(v.x * inv); o.y = f2bf(v.y * inv);
            o.z = f2bf(v.z * inv); o.w = f2bf(v.w * inv);
            int kt = d >> 5, kk = d & 31;
            int slot = (kk >> 3) * 16 + r, elem = kk & 7;
            *(ushort4*)(ob + (((size_t)(rt * ktiles + kt)) << 9) + slot * 8 + elem) = o;
        }
    }
    if (blockIdx.x == 0) {
        int t = threadIdx.x;
        for (int i = t; i < Nb; i += blockDim.x) mouth_word[i] = -1;
        for (int g = t; g < G; g += blockDim.x) {
            group_batch[g] = -1; group_is_mouth[g] = -1;
            numv[g] = 0.f; t1v[g] = 0.f; t3v[g] = 0.f;
        }
        __syncthreads();
        for (int j = t; j < Nd; j += blockDim.x) {
            int g = lower_bound_i(ut, G, td[j]);
            col_g[j] = g;
            atomicMax(&group_batch[g], bd[j]);
            atomicMax(&group_is_mouth[g], im[j]);
            if (im[j] == 1) atomicMax(&mouth_word[bd[j]], td[j]);
        }
        __syncthreads();
        for (int j = t; j < Nd; j += blockDim.x) {
            int g = col_g[j];
            col_gb[j] = group_batch[g];
            col_gm[j] = group_is_mouth[g];
            col_gc[j] = ut[g];
        }
    }
}

// ---------------- kernel 2: MFMA GEMM + fused epilogue ----------------
// grid (Nb/64, Nd/64), 256 threads = 4 waves (2x2), each wave a 32x32 tile (2x2 frags).
__global__ __launch_bounds__(256, 4)
void k_main(const unsigned short* __restrict__ fbt, const unsigned short* __restrict__ fdt,
            const int* __restrict__ tb, const int* __restrict__ bb_arr,
            const int* __restrict__ mouth_word,
            const int* __restrict__ col_g, const int* __restrict__ col_gb,
            const int* __restrict__ col_gm, const int* __restrict__ col_gc,
            int Nb, int Nd, int D,
            float* __restrict__ rowsumA, float* __restrict__ numv,
            float* __restrict__ t1v, float* __restrict__ t3v) {
    __shared__ float cnum[64], ct1[64], ct3[64], rsum[64];

    int t = threadIdx.x, lane = t & 63, wid = t >> 6;
    int wr = wid >> 1, wc = wid & 1;
    int bm = blockIdx.x * 64, bn = blockIdx.y * 64;
    int l15 = lane & 15, lhi = lane >> 4;

    if (t < 64) { cnum[t] = 0.f; ct1[t] = 0.f; ct3[t] = 0.f; rsum[t] = 0.f; }

    int ktiles = D >> 5;
    const unsigned short* a0p = fbt + (((size_t)(((bm >> 4) + wr * 2) * ktiles)) << 9) + lane * 8;
    const unsigned short* a1p = a0p + ((size_t)ktiles << 9);
    const unsigned short* b0p = fdt + (((size_t)(((bn >> 4) + wc * 2) * ktiles)) << 9) + lane * 8;
    const unsigned short* b1p = b0p + ((size_t)ktiles << 9);

    f32x4 acc[2][2] = {};
    #pragma unroll 8
    for (int kt = 0; kt < ktiles; ++kt) {
        size_t o = (size_t)kt << 9;
        bf16x8 a0 = *(const bf16x8*)(a0p + o);
        bf16x8 a1 = *(const bf16x8*)(a1p + o);
        bf16x8 b0 = *(const bf16x8*)(b0p + o);
        bf16x8 b1 = *(const bf16x8*)(b1p + o);
        acc[0][0] = __builtin_amdgcn_mfma_f32_16x16x32_bf16(a0, b0, acc[0][0], 0, 0, 0);
        acc[0][1] = __builtin_amdgcn_mfma_f32_16x16x32_bf16(a0, b1, acc[0][1], 0, 0, 0);
        acc[1][0] = __builtin_amdgcn_mfma_f32_16x16x32_bf16(a1, b0, acc[1][0], 0, 0, 0);
        acc[1][1] = __builtin_amdgcn_mfma_f32_16x16x32_bf16(a1, b1, acc[1][1], 0, 0, 0);
    }

    // ---- epilogue ----
    int cgb[2], cgm[2], cgc[2];
    #pragma unroll
    for (int nj = 0; nj < 2; ++nj) {
        int col = bn + wc * 32 + nj * 16 + l15;
        cgb[nj] = col_gb[col]; cgm[nj] = col_gm[col]; cgc[nj] = col_gc[col];
    }

    float pnum[2] = {0.f, 0.f}, pt1[2] = {0.f, 0.f}, pt3[2] = {0.f, 0.f};
    float prow[2][4];

    #pragma unroll
    for (int mi = 0; mi < 2; ++mi) {
        #pragma unroll
        for (int r = 0; r < 4; ++r) {
            int i = bm + wr * 32 + mi * 16 + lhi * 4 + r;
            int tbi = tb[i], bbi = bb_arr[i];
            int mw = mouth_word[bbi];
            bool fg = (tbi != -1);
            float pr = 0.f;
            #pragma unroll
            for (int nj = 0; nj < 2; ++nj) {
                float e = __expf(acc[mi][nj][r] * INVT - CSHIFT);
                bool match = fg ? (cgc[nj] == mw) : ((cgb[nj] == bbi) && (cgm[nj] == 0));
                float a = (match && (bbi != cgb[nj])) ? 0.f : e;
                pnum[nj] += match ? e : 0.f;
                pt1[nj] += a;
                pt3[nj] += match ? a : 0.f;
                pr += a;
            }
            prow[mi][r] = pr;
        }
    }

    __syncthreads();   // LDS zero-init visible

    // col reduce: lanes sharing a col differ in lhi -> xor 16, 32
    #pragma unroll
    for (int nj = 0; nj < 2; ++nj) {
        float n = pnum[nj], x1 = pt1[nj], x3 = pt3[nj];
        n  += __shfl_xor(n, 16, 64);  n  += __shfl_xor(n, 32, 64);
        x1 += __shfl_xor(x1, 16, 64); x1 += __shfl_xor(x1, 32, 64);
        x3 += __shfl_xor(x3, 16, 64); x3 += __shfl_xor(x3, 32, 64);
        if (lhi == 0) {
            int c = wc * 32 + nj * 16 + l15;
            atomicAdd(&cnum[c], n); atomicAdd(&ct1[c], x1); atomicAdd(&ct3[c], x3);
        }
    }
    // row reduce: lanes sharing a row differ in l15 -> xor 1,2,4,8
    #pragma unroll
    for (int mi = 0; mi < 2; ++mi) {
        #pragma unroll
        for (int r = 0; r < 4; ++r) {
            float v = prow[mi][r];
            v += __shfl_xor(v, 1, 64); v += __shfl_xor(v, 2, 64);
            v += __shfl_xor(v, 4, 64); v += __shfl_xor(v, 8, 64);
            if (l15 == 0) atomicAdd(&rsum[wr * 32 + mi * 16 + lhi * 4 + r], v);
        }
    }
    __syncthreads();

    if (t < 16) {
        int base = bn + t * 4;
        int g0 = col_g[base];
        float sn = cnum[4*t] + cnum[4*t+1] + cnum[4*t+2] + cnum[4*t+3];
        float s1 = ct1[4*t] + ct1[4*t+1] + ct1[4*t+2] + ct1[4*t+3];
        float s3 = ct3[4*t] + ct3[4*t+1] + ct3[4*t+2] + ct3[4*t+3];
        if (col_g[base+1] == g0 && col_g[base+2] == g0 && col_g[base+3] == g0) {
            atomicAdd(&numv[g0], sn); atomicAdd(&t1v[g0], s1); atomicAdd(&t3v[g0], s3);
        } else {
            #pragma unroll
            for (int c = 0; c < 4; ++c) {
                int g = col_g[base + c];
                atomicAdd(&numv[g], cnum[4*t+c]);
                atomicAdd(&t1v[g], ct1[4*t+c]);
                atomicAdd(&t3v[g], ct3[4*t+c]);
            }
        }
    } else if (t >= 64 && t < 128) {
        int r = t - 64;
        atomicAdd(&rowsumA[bm + r], rsum[r]);
    }
}

// ---------------- kernel 3: t2 + final loss (single block) ----------------
__global__ void k_finish(const int* __restrict__ tb, const int* __restrict__ bb_arr,
                         const int* __restrict__ mouth_word, const int* __restrict__ ut,
                         const int* __restrict__ group_batch, const int* __restrict__ group_is_mouth,
                         const float* __restrict__ rowsumA,
                         const float* __restrict__ numv, const float* __restrict__ t1v,
                         const float* __restrict__ t3v,
                         int Nb, int G, float* __restrict__ out) {
    __shared__ float t2g[1024];
    __shared__ float bgs[1024];
    __shared__ float red[256];
    int t = threadIdx.x;
    for (int i = t; i < 1024; i += 256) { t2g[i] = 0.f; bgs[i] = 0.f; }
    __syncthreads();
    for (int i = t; i < Nb; i += 256) {
        float r = rowsumA[i];
        int tbi = tb[i], bbi = bb_arr[i] & 1023;
        if (tbi != -1) {
            int g = lower_bound_i(ut, G, mouth_word[bbi]);
            atomicAdd(&t2g[g & 1023], r);
        } else {
            atomicAdd(&bgs[bbi], r);
        }
    }
    __syncthreads();
    float acc = 0.f;
    for (int g = t; g < G; g += 256) {
        float t2 = t2g[g & 1023];
        int gb = group_batch[g];
        if (group_is_mouth[g] == 0 && gb >= 0 && gb < 1024) t2 += bgs[gb];
        float den = t1v[g] + t2 - t3v[g];
        acc += logf(den) - logf(numv[g]);
    }
    red[t] = acc;
    __syncthreads();
    for (int k = 128; k >= 1; k >>= 1) {
        if (t < k) red[t] += red[t + k];
        __syncthreads();
    }
    if (t == 0) out[0] = red[0] / (float)G;
}

extern "C" void kernel_launch(void* const* d_in, const int* in_sizes, int n_in,
                              void* d_out, int out_size, void* d_ws, size_t ws_size,
                              hipStream_t stream) {
    const float* fb = (const float*)d_in[0];
    const float* fd = (const float*)d_in[1];
    const int* tb = (const int*)d_in[2];
    const int* td = (const int*)d_in[3];
    const int* bb = (const int*)d_in[4];
    const int* bd = (const int*)d_in[5];
    const int* im = (const int*)d_in[6];
    const int* ut = (const int*)d_in[7];

    int Nb = in_sizes[2];
    int Nd = in_sizes[3];
    int G  = in_sizes[7];
    int D  = in_sizes[0] / Nb;
    float* out = (float*)d_out;

    char* p = (char*)d_ws;
    unsigned short* fbt = (unsigned short*)p; p += (size_t)Nb * D * sizeof(unsigned short);
    unsigned short* fdt = (unsigned short*)p; p += (size_t)Nd * D * sizeof(unsigned short);
    float* rowsumA = (float*)p; p += (size_t)Nb * sizeof(float);
    float* numv = (float*)p;    p += (size_t)G * sizeof(float);
    float* t1v = (float*)p;     p += (size_t)G * sizeof(float);
    float* t3v = (float*)p;     p += (size_t)G * sizeof(float);
    int* mouth_word = (int*)p;     p += (size_t)Nb * sizeof(int);
    int* group_batch = (int*)p;    p += (size_t)G * sizeof(int);
    int* group_is_mouth = (int*)p; p += (size_t)G * sizeof(int);
    int* col_g = (int*)p;  p += (size_t)Nd * sizeof(int);
    int* col_gb = (int*)p; p += (size_t)Nd * sizeof(int);
    int* col_gm = (int*)p; p += (size_t)Nd * sizeof(int);
    int* col_gc = (int*)p; p += (size_t)Nd * sizeof(int);

    {
        int waves = Nb + Nd;
        int blocks = (waves + 3) / 4;
        k_prep<<<blocks, 256, 0, stream>>>(fb, fd, Nb, Nd, D, fbt, fdt, rowsumA,
                                           td, bd, im, ut, G,
                                           mouth_word, group_batch, group_is_mouth,
                                           col_g, col_gb, col_gm, col_gc,
                                           numv, t1v, t3v);
    }

    dim3 grid(Nb / 64, Nd / 64);
    k_main<<<grid, 256, 0, stream>>>(fbt, fdt, tb, bb, mouth_word,
                                     col_g, col_gb, col_gm, col_gc,
                                     Nb, Nd, D, rowsumA, numv, t1v, t3v);

    k_finish<<<1, 256, 0, stream>>>(tb, bb, mouth_word, ut, group_batch, group_is_mouth,
                                    rowsumA, numv, t1v, t3v, Nb, G, out);
}

// Round 6
// 59.133 us; speedup vs baseline: 2.0884x; 1.0844x over previous
//
#include <hip/hip_runtime.h>
#include <math.h>

#define INVT (1.0f / 0.07f)
#define CSHIFT (1.0f / 0.07f)

using bf16x8 = __attribute__((ext_vector_type(8))) short;
using f32x4  = __attribute__((ext_vector_type(4))) float;

__device__ __forceinline__ int lower_bound_i(const int* a, int n, int v) {
    int lo = 0, hi = n;
    while (lo < hi) { int mid = (lo + hi) >> 1; if (a[mid] < v) lo = mid + 1; else hi = mid; }
    return lo;
}

__device__ __forceinline__ unsigned short f2bf(float x) {
    unsigned int u = __float_as_uint(x);
    unsigned int r = (u + 0x7fffu + ((u >> 16) & 1u)) >> 16;   // RNE
    return (unsigned short)r;
}

__device__ __forceinline__ float agent_ld(const float* p) {
    return __hip_atomic_load(p, __ATOMIC_RELAXED, __HIP_MEMORY_SCOPE_AGENT);
}

// ---------------- kernel 1: normalize + bf16 tiled convert + zero + meta ----------------
// Tile = (16 rows x 32 k) = 512 bf16 (1KB). Slot s holds row s&15, k-chunk (s>>4)*8.
// => k_main lane l does one 16B load at tile_base + l*16: perfectly coalesced.
__global__ void k_prep(const float* __restrict__ fb, const float* __restrict__ fd,
                       int Nb, int Nd, int D,
                       unsigned short* __restrict__ fbt, unsigned short* __restrict__ fdt,
                       float* __restrict__ rowsumA, float* __restrict__ colacc,
                       const int* __restrict__ td, const int* __restrict__ bd,
                       const int* __restrict__ im,
                       int* __restrict__ mouth_word, unsigned int* __restrict__ done) {
    // distributed zeroing of accumulators
    int zidx = blockIdx.x * blockDim.x + threadIdx.x;
    int zf = Nb + 3 * Nd;
    if (zidx < Nb) rowsumA[zidx] = 0.f;
    else if (zidx < zf) colacc[zidx - Nb] = 0.f;
    else if (zidx == zf) *done = 0u;

    int gw = zidx >> 6;
    int lane = threadIdx.x & 63;
    int ktiles = D >> 5;
    if (gw < Nb + Nd) {
        const float* row; unsigned short* ob; int rt, r;
        if (gw < Nb) {
            row = fb + (size_t)gw * D; ob = fbt; rt = gw >> 4; r = gw & 15;
        } else {
            int j = gw - Nb;
            row = fd + (size_t)j * D; ob = fdt; rt = j >> 4; r = j & 15;
        }
        float s = 0.f;
        for (int d = lane * 4; d < D; d += 256) {
            float4 v = *(const float4*)(row + d);
            s += v.x * v.x + v.y * v.y + v.z * v.z + v.w * v.w;
        }
        #pragma unroll
        for (int m = 32; m >= 1; m >>= 1) s += __shfl_xor(s, m, 64);
        float inv = rsqrtf(s);
        for (int d = lane * 4; d < D; d += 256) {
            float4 v = *(const float4*)(row + d);
            ushort4 o;
            o.x = f2bf(v.x * inv); o.y = f2bf(v.y * inv);
            o.z = f2bf(v.z * inv); o.w = f2bf(v.w * inv);
            int kt = d >> 5, kk = d & 31;
            int slot = (kk >> 3) * 16 + r, elem = kk & 7;
            *(ushort4*)(ob + (((size_t)(rt * ktiles + kt)) << 9) + slot * 8 + elem) = o;
        }
    }
    if (blockIdx.x == 0) {
        int t = threadIdx.x;
        for (int i = t; i < Nb; i += blockDim.x) mouth_word[i] = -1;
        __syncthreads();
        for (int j = t; j < Nd; j += blockDim.x) {
            if (im[j] == 1) atomicMax(&mouth_word[bd[j]], td[j]);
        }
    }
}

// ---------------- kernel 2: MFMA GEMM + fused epilogue + fence-free last-block finish ----------------
__global__ __launch_bounds__(256, 4)
void k_main(const unsigned short* __restrict__ fbt, const unsigned short* __restrict__ fdt,
            const int* __restrict__ tb, const int* __restrict__ bb_arr,
            const int* __restrict__ td, const int* __restrict__ bd,
            const int* __restrict__ im, const int* __restrict__ ut,
            const int* __restrict__ mouth_word,
            int Nb, int Nd, int D, int G, int nblk,
            float* __restrict__ rowsumA, float* __restrict__ numc,
            float* __restrict__ t1c, float* __restrict__ t3c,
            unsigned int* __restrict__ done, float* __restrict__ out) {
    __shared__ float cnum[64], ct1[64], ct3[64], rsum[64];
    __shared__ int lastflag;

    int t = threadIdx.x, lane = t & 63, wid = t >> 6;
    int wr = wid >> 1, wc = wid & 1;
    int bm = blockIdx.x * 64, bn = blockIdx.y * 64;
    int l15 = lane & 15, lhi = lane >> 4;

    if (t < 64) { cnum[t] = 0.f; ct1[t] = 0.f; ct3[t] = 0.f; rsum[t] = 0.f; }

    int ktiles = D >> 5;
    const unsigned short* a0p = fbt + (((size_t)(((bm >> 4) + wr * 2) * ktiles)) << 9) + lane * 8;
    const unsigned short* a1p = a0p + ((size_t)ktiles << 9);
    const unsigned short* b0p = fdt + (((size_t)(((bn >> 4) + wc * 2) * ktiles)) << 9) + lane * 8;
    const unsigned short* b1p = b0p + ((size_t)ktiles << 9);

    f32x4 acc[2][2] = {};
    #pragma unroll 8
    for (int kt = 0; kt < ktiles; ++kt) {
        size_t o = (size_t)kt << 9;
        bf16x8 a0 = *(const bf16x8*)(a0p + o);
        bf16x8 a1 = *(const bf16x8*)(a1p + o);
        bf16x8 b0 = *(const bf16x8*)(b0p + o);
        bf16x8 b1 = *(const bf16x8*)(b1p + o);
        acc[0][0] = __builtin_amdgcn_mfma_f32_16x16x32_bf16(a0, b0, acc[0][0], 0, 0, 0);
        acc[0][1] = __builtin_amdgcn_mfma_f32_16x16x32_bf16(a0, b1, acc[0][1], 0, 0, 0);
        acc[1][0] = __builtin_amdgcn_mfma_f32_16x16x32_bf16(a1, b0, acc[1][0], 0, 0, 0);
        acc[1][1] = __builtin_amdgcn_mfma_f32_16x16x32_bf16(a1, b1, acc[1][1], 0, 0, 0);
    }

    // ---- epilogue: col meta is raw arrays (constant within a dict group) ----
    int cgb[2], cgm[2], cgc[2];
    #pragma unroll
    for (int nj = 0; nj < 2; ++nj) {
        int col = bn + wc * 32 + nj * 16 + l15;
        cgb[nj] = bd[col]; cgm[nj] = im[col]; cgc[nj] = td[col];
    }

    float pnum[2] = {0.f, 0.f}, pt1[2] = {0.f, 0.f}, pt3[2] = {0.f, 0.f};
    float prow[2][4];

    #pragma unroll
    for (int mi = 0; mi < 2; ++mi) {
        #pragma unroll
        for (int r = 0; r < 4; ++r) {
            int i = bm + wr * 32 + mi * 16 + lhi * 4 + r;
            int tbi = tb[i], bbi = bb_arr[i];
            int mw = mouth_word[bbi];
            bool fg = (tbi != -1);
            float pr = 0.f;
            #pragma unroll
            for (int nj = 0; nj < 2; ++nj) {
                float e = __expf(acc[mi][nj][r] * INVT - CSHIFT);
                bool match = fg ? (cgc[nj] == mw) : ((cgb[nj] == bbi) && (cgm[nj] == 0));
                float a = (match && (bbi != cgb[nj])) ? 0.f : e;
                pnum[nj] += match ? e : 0.f;
                pt1[nj] += a;
                pt3[nj] += match ? a : 0.f;
                pr += a;
            }
            prow[mi][r] = pr;
        }
    }

    __syncthreads();   // LDS zero-init visible

    #pragma unroll
    for (int nj = 0; nj < 2; ++nj) {
        float n = pnum[nj], x1 = pt1[nj], x3 = pt3[nj];
        n  += __shfl_xor(n, 16, 64);  n  += __shfl_xor(n, 32, 64);
        x1 += __shfl_xor(x1, 16, 64); x1 += __shfl_xor(x1, 32, 64);
        x3 += __shfl_xor(x3, 16, 64); x3 += __shfl_xor(x3, 32, 64);
        if (lhi == 0) {
            int c = wc * 32 + nj * 16 + l15;
            atomicAdd(&cnum[c], n); atomicAdd(&ct1[c], x1); atomicAdd(&ct3[c], x3);
        }
    }
    #pragma unroll
    for (int mi = 0; mi < 2; ++mi) {
        #pragma unroll
        for (int r = 0; r < 4; ++r) {
            float v = prow[mi][r];
            v += __shfl_xor(v, 1, 64); v += __shfl_xor(v, 2, 64);
            v += __shfl_xor(v, 4, 64); v += __shfl_xor(v, 8, 64);
            if (l15 == 0) atomicAdd(&rsum[wr * 32 + mi * 16 + lhi * 4 + r], v);
        }
    }
    __syncthreads();

    if (t < 64) {
        atomicAdd(&numc[bn + t], cnum[t]);
        atomicAdd(&t1c[bn + t], ct1[t]);
        atomicAdd(&t3c[bn + t], ct3[t]);
    } else if (t < 128) {
        atomicAdd(&rowsumA[bm + (t - 64)], rsum[t - 64]);
    }

    // ---- fence-free handoff: drain own atomics (waitcnt only, NO cache flush) ----
    asm volatile("s_waitcnt vmcnt(0)" ::: "memory");
    __syncthreads();
    if (t == 0) {
        unsigned int old = atomicAdd(done, 1u);
        lastflag = (old == (unsigned int)(nblk - 1)) ? 1 : 0;
    }
    __syncthreads();
    if (!lastflag) return;

    // ---- last block: t2 + group reduction + loss ----
    __shared__ float t2g[1024], bgs[1024], red[256];
    for (int i = t; i < 1024; i += 256) { t2g[i] = 0.f; bgs[i] = 0.f; }
    __syncthreads();
    for (int i = t; i < Nb; i += 256) {
        float r = agent_ld(&rowsumA[i]);
        int tbi = tb[i], bbi = bb_arr[i] & 1023;
        if (tbi != -1) {
            int g = lower_bound_i(ut, G, mouth_word[bbi]);
            atomicAdd(&t2g[g & 1023], r);
        } else {
            atomicAdd(&bgs[bbi], r);
        }
    }
    __syncthreads();
    float acc2 = 0.f;
    for (int g = t; g < G; g += 256) {
        int s = lower_bound_i(td, Nd, ut[g]);
        int e = (g + 1 < G) ? lower_bound_i(td, Nd, ut[g + 1]) : Nd;
        float sn = 0.f, s1 = 0.f, s3 = 0.f;
        for (int c = s; c < e; ++c) {
            sn += agent_ld(&numc[c]);
            s1 += agent_ld(&t1c[c]);
            s3 += agent_ld(&t3c[c]);
        }
        int gb = bd[s], gm = im[s];
        float t2 = t2g[g & 1023];
        if (gm == 0 && gb >= 0 && gb < 1024) t2 += bgs[gb];
        acc2 += logf(s1 + t2 - s3) - logf(sn);
    }
    red[t] = acc2;
    __syncthreads();
    for (int k = 128; k >= 1; k >>= 1) {
        if (t < k) red[t] += red[t + k];
        __syncthreads();
    }
    if (t == 0) out[0] = red[0] / (float)G;
}

extern "C" void kernel_launch(void* const* d_in, const int* in_sizes, int n_in,
                              void* d_out, int out_size, void* d_ws, size_t ws_size,
                              hipStream_t stream) {
    const float* fb = (const float*)d_in[0];
    const float* fd = (const float*)d_in[1];
    const int* tb = (const int*)d_in[2];
    const int* td = (const int*)d_in[3];
    const int* bb = (const int*)d_in[4];
    const int* bd = (const int*)d_in[5];
    const int* im = (const int*)d_in[6];
    const int* ut = (const int*)d_in[7];

    int Nb = in_sizes[2];
    int Nd = in_sizes[3];
    int G  = in_sizes[7];
    int D  = in_sizes[0] / Nb;
    float* out = (float*)d_out;

    char* p = (char*)d_ws;
    unsigned short* fbt = (unsigned short*)p; p += (size_t)Nb * D * sizeof(unsigned short);
    unsigned short* fdt = (unsigned short*)p; p += (size_t)Nd * D * sizeof(unsigned short);
    float* rowsumA = (float*)p; p += (size_t)Nb * sizeof(float);
    float* colacc = (float*)p;  p += (size_t)3 * Nd * sizeof(float);
    float* numc = colacc;
    float* t1c = colacc + Nd;
    float* t3c = colacc + 2 * Nd;
    int* mouth_word = (int*)p; p += (size_t)Nb * sizeof(int);
    unsigned int* done = (unsigned int*)p; p += sizeof(unsigned int);

    {
        int waves = Nb + Nd;
        int blocks = (waves + 3) / 4;
        k_prep<<<blocks, 256, 0, stream>>>(fb, fd, Nb, Nd, D, fbt, fdt,
                                           rowsumA, colacc, td, bd, im,
                                           mouth_word, done);
    }

    dim3 grid(Nb / 64, Nd / 64);
    int nblk = (Nb / 64) * (Nd / 64);
    k_main<<<grid, 256, 0, stream>>>(fbt, fdt, tb, bb, td, bd, im, ut, mouth_word,
                                     Nb, Nd, D, G, nblk,
                                     rowsumA, numc, t1c, t3c, done, out);
}

// Round 7
// 54.194 us; speedup vs baseline: 2.2787x; 1.0911x over previous
//
#include <hip/hip_runtime.h>
#include <math.h>

#define INVT (1.0f / 0.07f)
#define CSHIFT (1.0f / 0.07f)

using bf16x8 = __attribute__((ext_vector_type(8))) short;
using f32x4  = __attribute__((ext_vector_type(4))) float;

__device__ __forceinline__ int lower_bound_i(const int* a, int n, int v) {
    int lo = 0, hi = n;
    while (lo < hi) { int mid = (lo + hi) >> 1; if (a[mid] < v) lo = mid + 1; else hi = mid; }
    return lo;
}

__device__ __forceinline__ unsigned short f2bf(float x) {
    unsigned int u = __float_as_uint(x);
    unsigned int r = (u + 0x7fffu + ((u >> 16) & 1u)) >> 16;   // RNE
    return (unsigned short)r;
}

__device__ __forceinline__ float agent_ld(const float* p) {
    return __hip_atomic_load(p, __ATOMIC_RELAXED, __HIP_MEMORY_SCOPE_AGENT);
}

// ---------------- kernel 1: normalize + bf16 tiled convert + zero + meta ----------------
// Tile = (16 rows x 32 k) = 512 bf16 (1KB). Slot s holds row s&15, k-chunk (s>>4)*8.
__global__ void k_prep(const float* __restrict__ fb, const float* __restrict__ fd,
                       int Nb, int Nd, int D,
                       unsigned short* __restrict__ fbt, unsigned short* __restrict__ fdt,
                       float* __restrict__ rowpart, float* __restrict__ colpart,
                       unsigned int* __restrict__ dcnt,
                       const int* __restrict__ td, const int* __restrict__ bd,
                       const int* __restrict__ im,
                       int* __restrict__ mouth_word) {
    // distributed zeroing: rowpart[4*Nb], colpart[24*Nd], dcnt[1025]
    int zidx = blockIdx.x * blockDim.x + threadIdx.x;
    int z1 = 4 * Nb, z2 = z1 + 24 * Nd, z3 = z2 + 1025;
    if (zidx < z1) rowpart[zidx] = 0.f;
    else if (zidx < z2) colpart[zidx - z1] = 0.f;
    else if (zidx < z3) dcnt[zidx - z2] = 0u;

    int gw = zidx >> 6;
    int lane = threadIdx.x & 63;
    int ktiles = D >> 5;
    if (gw < Nb + Nd) {
        const float* row; unsigned short* ob; int rt, r;
        if (gw < Nb) {
            row = fb + (size_t)gw * D; ob = fbt; rt = gw >> 4; r = gw & 15;
        } else {
            int j = gw - Nb;
            row = fd + (size_t)j * D; ob = fdt; rt = j >> 4; r = j & 15;
        }
        float s = 0.f;
        for (int d = lane * 4; d < D; d += 256) {
            float4 v = *(const float4*)(row + d);
            s += v.x * v.x + v.y * v.y + v.z * v.z + v.w * v.w;
        }
        #pragma unroll
        for (int m = 32; m >= 1; m >>= 1) s += __shfl_xor(s, m, 64);
        float inv = rsqrtf(s);
        for (int d = lane * 4; d < D; d += 256) {
            float4 v = *(const float4*)(row + d);
            ushort4 o;
            o.x = f2bf(v.x * inv); o.y = f2bf(v.y * inv);
            o.z = f2bf(v.z * inv); o.w = f2bf(v.w * inv);
            int kt = d >> 5, kk = d & 31;
            int slot = (kk >> 3) * 16 + r, elem = kk & 7;
            *(ushort4*)(ob + (((size_t)(rt * ktiles + kt)) << 9) + slot * 8 + elem) = o;
        }
    }
    if (blockIdx.x == 0) {
        int t = threadIdx.x;
        for (int i = t; i < Nb; i += blockDim.x) mouth_word[i] = -1;
        __syncthreads();
        for (int j = t; j < Nd; j += blockDim.x) {
            if (im[j] == 1) atomicMax(&mouth_word[bd[j]], td[j]);
        }
    }
}

// ---------------- kernel 2: MFMA GEMM + fused epilogue + fence-free last-block finish ----------------
__global__ __launch_bounds__(256, 4)
void k_main(const unsigned short* __restrict__ fbt, const unsigned short* __restrict__ fdt,
            const int* __restrict__ tb, const int* __restrict__ bb_arr,
            const int* __restrict__ td, const int* __restrict__ bd,
            const int* __restrict__ im, const int* __restrict__ ut,
            const int* __restrict__ mouth_word,
            int Nb, int Nd, int D, int G,
            float* __restrict__ rowpart, float* __restrict__ colpart,
            unsigned int* __restrict__ dcnt, float* __restrict__ out) {
    __shared__ float cnum[64], ct1[64], ct3[64], rsum[64];
    __shared__ int lastflag;

    int t = threadIdx.x, lane = t & 63, wid = t >> 6;
    int wr = wid >> 1, wc = wid & 1;
    int bm = blockIdx.x * 64, bn = blockIdx.y * 64;
    int l15 = lane & 15, lhi = lane >> 4;

    if (t < 64) { cnum[t] = 0.f; ct1[t] = 0.f; ct3[t] = 0.f; rsum[t] = 0.f; }

    int ktiles = D >> 5;
    const unsigned short* a0p = fbt + (((size_t)(((bm >> 4) + wr * 2) * ktiles)) << 9) + lane * 8;
    const unsigned short* a1p = a0p + ((size_t)ktiles << 9);
    const unsigned short* b0p = fdt + (((size_t)(((bn >> 4) + wc * 2) * ktiles)) << 9) + lane * 8;
    const unsigned short* b1p = b0p + ((size_t)ktiles << 9);

    f32x4 acc[2][2] = {};
    #pragma unroll 8
    for (int kt = 0; kt < ktiles; ++kt) {
        size_t o = (size_t)kt << 9;
        bf16x8 a0 = *(const bf16x8*)(a0p + o);
        bf16x8 a1 = *(const bf16x8*)(a1p + o);
        bf16x8 b0 = *(const bf16x8*)(b0p + o);
        bf16x8 b1 = *(const bf16x8*)(b1p + o);
        acc[0][0] = __builtin_amdgcn_mfma_f32_16x16x32_bf16(a0, b0, acc[0][0], 0, 0, 0);
        acc[0][1] = __builtin_amdgcn_mfma_f32_16x16x32_bf16(a0, b1, acc[0][1], 0, 0, 0);
        acc[1][0] = __builtin_amdgcn_mfma_f32_16x16x32_bf16(a1, b0, acc[1][0], 0, 0, 0);
        acc[1][1] = __builtin_amdgcn_mfma_f32_16x16x32_bf16(a1, b1, acc[1][1], 0, 0, 0);
    }

    // ---- epilogue: col meta is raw arrays (constant within a dict group) ----
    int cgb[2], cgm[2], cgc[2];
    #pragma unroll
    for (int nj = 0; nj < 2; ++nj) {
        int col = bn + wc * 32 + nj * 16 + l15;
        cgb[nj] = bd[col]; cgm[nj] = im[col]; cgc[nj] = td[col];
    }

    float pnum[2] = {0.f, 0.f}, pt1[2] = {0.f, 0.f}, pt3[2] = {0.f, 0.f};
    float prow[2][4];

    #pragma unroll
    for (int mi = 0; mi < 2; ++mi) {
        #pragma unroll
        for (int r = 0; r < 4; ++r) {
            int i = bm + wr * 32 + mi * 16 + lhi * 4 + r;
            int tbi = tb[i], bbi = bb_arr[i];
            int mw = mouth_word[bbi];
            bool fg = (tbi != -1);
            float pr = 0.f;
            #pragma unroll
            for (int nj = 0; nj < 2; ++nj) {
                float e = __expf(acc[mi][nj][r] * INVT - CSHIFT);
                bool match = fg ? (cgc[nj] == mw) : ((cgb[nj] == bbi) && (cgm[nj] == 0));
                float a = (match && (bbi != cgb[nj])) ? 0.f : e;
                pnum[nj] += match ? e : 0.f;
                pt1[nj] += a;
                pt3[nj] += match ? a : 0.f;
                pr += a;
            }
            prow[mi][r] = pr;
        }
    }

    __syncthreads();   // LDS zero-init visible

    #pragma unroll
    for (int nj = 0; nj < 2; ++nj) {
        float n = pnum[nj], x1 = pt1[nj], x3 = pt3[nj];
        n  += __shfl_xor(n, 16, 64);  n  += __shfl_xor(n, 32, 64);
        x1 += __shfl_xor(x1, 16, 64); x1 += __shfl_xor(x1, 32, 64);
        x3 += __shfl_xor(x3, 16, 64); x3 += __shfl_xor(x3, 32, 64);
        if (lhi == 0) {
            int c = wc * 32 + nj * 16 + l15;
            atomicAdd(&cnum[c], n); atomicAdd(&ct1[c], x1); atomicAdd(&ct3[c], x3);
        }
    }
    #pragma unroll
    for (int mi = 0; mi < 2; ++mi) {
        #pragma unroll
        for (int r = 0; r < 4; ++r) {
            float v = prow[mi][r];
            v += __shfl_xor(v, 1, 64); v += __shfl_xor(v, 2, 64);
            v += __shfl_xor(v, 4, 64); v += __shfl_xor(v, 8, 64);
            if (l15 == 0) atomicAdd(&rsum[wr * 32 + mi * 16 + lhi * 4 + r], v);
        }
    }
    __syncthreads();

    // partitioned global accumulation: col partition by bx&7, row partition by by&3
    float* cp = colpart + (size_t)(blockIdx.x & 7) * 3 * Nd;
    if (t < 64) {
        atomicAdd(&cp[bn + t], cnum[t]);
        atomicAdd(&cp[Nd + bn + t], ct1[t]);
        atomicAdd(&cp[2 * Nd + bn + t], ct3[t]);
    } else if (t < 128) {
        atomicAdd(&rowpart[(size_t)(blockIdx.y & 3) * Nb + bm + (t - 64)], rsum[t - 64]);
    }

    // ---- fence-free hierarchical handoff (atomics only, NO cache flush) ----
    asm volatile("s_waitcnt vmcnt(0)" ::: "memory");
    __syncthreads();
    if (t == 0) {
        int lf = 0;
        unsigned int old = atomicAdd(&dcnt[blockIdx.x * 16], 1u);   // padded: 1 line per bx
        if (old == gridDim.y - 1) {
            unsigned int old2 = atomicAdd(&dcnt[1024], 1u);
            lf = (old2 == gridDim.x - 1) ? 1 : 0;
        }
        lastflag = lf;
    }
    __syncthreads();
    if (!lastflag) return;

    // ---- last block: merge partials, t2, group reduction, loss ----
    __shared__ float t2g[1024], bgs[1024], red[256];
    for (int i = t; i < 1024; i += 256) { t2g[i] = 0.f; bgs[i] = 0.f; }
    __syncthreads();
    for (int i = t; i < Nb; i += 256) {
        float r = agent_ld(&rowpart[i]) + agent_ld(&rowpart[Nb + i])
                + agent_ld(&rowpart[2 * Nb + i]) + agent_ld(&rowpart[3 * Nb + i]);
        int tbi = tb[i], bbi = bb_arr[i] & 1023;
        if (tbi != -1) {
            int g = lower_bound_i(ut, G, mouth_word[bbi]);
            atomicAdd(&t2g[g & 1023], r);
        } else {
            atomicAdd(&bgs[bbi], r);
        }
    }
    __syncthreads();
    float acc2 = 0.f;
    for (int g = t; g < G; g += 256) {
        int s = lower_bound_i(td, Nd, ut[g]);
        int e = (g + 1 < G) ? lower_bound_i(td, Nd, ut[g + 1]) : Nd;
        float sn = 0.f, s1 = 0.f, s3 = 0.f;
        for (int c = s; c < e; ++c) {
            #pragma unroll
            for (int p = 0; p < 8; ++p) {
                const float* base = colpart + (size_t)p * 3 * Nd;
                sn += agent_ld(&base[c]);
                s1 += agent_ld(&base[Nd + c]);
                s3 += agent_ld(&base[2 * Nd + c]);
            }
        }
        int gb = bd[s], gm = im[s];
        float t2 = t2g[g & 1023];
        if (gm == 0 && gb >= 0 && gb < 1024) t2 += bgs[gb];
        acc2 += logf(s1 + t2 - s3) - logf(sn);
    }
    red[t] = acc2;
    __syncthreads();
    for (int k = 128; k >= 1; k >>= 1) {
        if (t < k) red[t] += red[t + k];
        __syncthreads();
    }
    if (t == 0) out[0] = red[0] / (float)G;
}

extern "C" void kernel_launch(void* const* d_in, const int* in_sizes, int n_in,
                              void* d_out, int out_size, void* d_ws, size_t ws_size,
                              hipStream_t stream) {
    const float* fb = (const float*)d_in[0];
    const float* fd = (const float*)d_in[1];
    const int* tb = (const int*)d_in[2];
    const int* td = (const int*)d_in[3];
    const int* bb = (const int*)d_in[4];
    const int* bd = (const int*)d_in[5];
    const int* im = (const int*)d_in[6];
    const int* ut = (const int*)d_in[7];

    int Nb = in_sizes[2];
    int Nd = in_sizes[3];
    int G  = in_sizes[7];
    int D  = in_sizes[0] / Nb;
    float* out = (float*)d_out;

    char* p = (char*)d_ws;
    unsigned short* fbt = (unsigned short*)p; p += (size_t)Nb * D * sizeof(unsigned short);
    unsigned short* fdt = (unsigned short*)p; p += (size_t)Nd * D * sizeof(unsigned short);
    float* rowpart = (float*)p; p += (size_t)4 * Nb * sizeof(float);
    float* colpart = (float*)p; p += (size_t)24 * Nd * sizeof(float);
    int* mouth_word = (int*)p;  p += (size_t)Nb * sizeof(int);
    unsigned int* dcnt = (unsigned int*)p; p += 1025 * sizeof(unsigned int);

    {
        int waves = Nb + Nd;
        int blocks = (waves + 3) / 4;
        k_prep<<<blocks, 256, 0, stream>>>(fb, fd, Nb, Nd, D, fbt, fdt,
                                           rowpart, colpart, dcnt,
                                           td, bd, im, mouth_word);
    }

    dim3 grid(Nb / 64, Nd / 64);
    k_main<<<grid, 256, 0, stream>>>(fbt, fdt, tb, bb, td, bd, im, ut, mouth_word,
                                     Nb, Nd, D, G,
                                     rowpart, colpart, dcnt, out);
}